// Round 17
// baseline (64.578 us; speedup 1.0000x reference)
//
#include <hip/hip_runtime.h>
#include <hip/hip_bf16.h>
#include <math.h>

static constexpr int B_ = 4;
static constexpr int C_ = 256;
static constexpr int PD_ = 64;
static constexpr int N_ = 4096;
static constexpr int O96_ = 96;
static constexpr float EPS_ = 1e-5f;
static constexpr float SCALE_ = 0.25f;   // 16^-0.5
static constexpr float LOG2E_ = 1.4426950408889634f;

typedef __attribute__((ext_vector_type(8))) short short8v;
typedef __attribute__((ext_vector_type(4))) float f32x4;

__device__ inline short f2bf(float x) {
    __hip_bfloat16 h = __float2bfloat16(x);   // hw RNE cvt
    short r; __builtin_memcpy(&r, &h, 2); return r;
}
__device__ inline float bf2f(short s) {
    union { float f; unsigned u; } v; v.u = ((unsigned)(unsigned short)s) << 16;
    return v.f;
}
__device__ inline unsigned pack_bf2(float lo, float hi) {
    return ((unsigned)(unsigned short)f2bf(hi) << 16) | (unsigned)(unsigned short)f2bf(lo);
}
__device__ inline float silu_(float v) { return v / (1.0f + __expf(-v)); }
__device__ inline float exp2_fast(float x) {
#if __has_builtin(__builtin_amdgcn_exp2f)
    return __builtin_amdgcn_exp2f(x);
#else
    return __expf(x * 0.6931471805599453f);
#endif
}

// ------- fused: blocks 0-255 GroupNorm partial sums (float4); 256-511 proj-weight cvt -------
__global__ __launch_bounds__(256) void k_gnw(const float* __restrict__ x,
        float* __restrict__ part,
        const float* __restrict__ pw,  const float* __restrict__ bnw,
        const float* __restrict__ bnb, const float* __restrict__ rm,
        const float* __restrict__ rv,  short* __restrict__ wbf,
        float* __restrict__ beta) {
    if (blockIdx.x >= 256) {               // ---- wcvt ----
        const int idx = (blockIdx.x - 256) * 256 + threadIdx.x;   // 0..65535
        const int o = idx >> 8, c = idx & 255;
        const float inv = bnw[o] * rsqrtf(rv[o] + EPS_);
        wbf[idx] = f2bf(pw[idx] * inv);
        if (c == 0) beta[o] = bnb[o] - rm[o] * inv;
        return;
    }
    const int blk = blockIdx.x;            // b*64 + c
    const int b = blk >> 6, c = blk & 63;
    const float4* p4 = (const float4*)(x + (size_t)(b * C_ + c) * N_);
    float s = 0.f, q = 0.f;
    #pragma unroll
    for (int i = 0; i < 4; ++i) {
        float4 v = p4[threadIdx.x + i * 256];
        s += v.x + v.y + v.z + v.w;
        q += v.x * v.x + v.y * v.y + v.z * v.z + v.w * v.w;
    }
    for (int d = 1; d < 64; d <<= 1) {
        s += __shfl_xor(s, d, 64);
        q += __shfl_xor(q, d, 64);
    }
    __shared__ float ls[4], lq[4];
    const int lane = threadIdx.x & 63, wid = threadIdx.x >> 6;
    if (lane == 0) { ls[wid] = s; lq[wid] = q; }
    __syncthreads();
    if (threadIdx.x == 0) {
        part[2 * blk]     = ls[0] + ls[1] + ls[2] + ls[3];
        part[2 * blk + 1] = lq[0] + lq[1] + lq[2] + lq[3];
    }
}

// ------- qkv as bf16 MFMA GEMM: GN+BN fully folded into w''/bias2 (R16 form) ------
__global__ __launch_bounds__(512) void k_qkv(const float* __restrict__ x,
        const float* __restrict__ gnw, const float* __restrict__ gnb,
        const float* __restrict__ qw,  const float* __restrict__ bnw,
        const float* __restrict__ bnb, const float* __restrict__ rm,
        const float* __restrict__ rv,  const float* __restrict__ part,
        short* __restrict__ qT, short* __restrict__ kfrag, short* __restrict__ vfrag) {
    __shared__ __align__(16) short wfrag[6][2][512];  // 12 KB  [ot][kk][(g*16+col)*8+j]
    __shared__ __align__(16) short xfrag[64][64];     // 8 KB   [n][(c8^(n&7))*8 + (c&7)]
    __shared__ float bias2[96];
    __shared__ float musr[2];
    const int t = threadIdx.x;
    const int b = blockIdx.x >> 6;
    const int n0 = (blockIdx.x & 63) << 6;
    if (t < 64) {                          // folded gn_fin
        float s = part[2 * (b * 64 + t)];
        float q = part[2 * (b * 64 + t) + 1];
        for (int d = 1; d < 64; d <<= 1) {
            s += __shfl_xor(s, d, 64);
            q += __shfl_xor(q, d, 64);
        }
        if (t == 0) {
            const float inv_n = 1.0f / (float)(PD_ * N_);
            float mu = s * inv_n;
            float var = q * inv_n - mu * mu;
            musr[0] = mu;
            musr[1] = rsqrtf(var + EPS_);
        }
    }
    {   // stage raw x1 tile -> bf16 xfrag (GN folded into weights, not here)
        const int nq = t & 15, c0 = t >> 4;            // c0 0..31
        #pragma unroll
        for (int pass = 0; pass < 2; ++pass) {
            const int c = c0 + pass * 32;
            float4 v4 = *(const float4*)(x + ((size_t)(b * C_ + c)) * N_ + n0 + nq * 4);
            const int c8 = c >> 3, cj = c & 7;
            float vv[4] = {v4.x, v4.y, v4.z, v4.w};
            #pragma unroll
            for (int e = 0; e < 4; ++e) {
                const int n = nq * 4 + e;
                xfrag[n][((c8 ^ (n & 7)) << 3) + cj] = f2bf(vv[e]);
            }
        }
    }
    __syncthreads();
    const float mu = musr[0], rs = musr[1];
    if (t < 96) {                          // build w'' fragments + bias2
        const int o = t;
        float inv  = bnw[o] * rsqrtf(rv[o] + EPS_);
        float bet  = bnb[o] - rm[o] * inv;
        if (o < 16) { inv *= SCALE_ * LOG2E_; bet *= SCALE_ * LOG2E_; }
        const float* wr = qw + o * PD_;
        const int ot = o >> 4, colo = o & 15;
        float bacc = 0.f;
        #pragma unroll
        for (int c = 0; c < PD_; ++c) {
            const float ga = rs * gnw[c];
            const float gb = gnb[c] - mu * ga;
            const float wv = wr[c];
            bacc += wv * gb;
            wfrag[ot][c >> 5][((((c >> 3) & 3) * 16 + colo) << 3) + (c & 7)] = f2bf(wv * ga * inv);
        }
        bias2[o] = bet + inv * bacc;
    }
    __syncthreads();
    // MFMA: wave w: n-tile nt2 = w&3, o-half oh = w>>2 (ot = 3*oh .. 3*oh+2)
    const int w = t >> 6, lane = t & 63;
    const int col = lane & 15, g = lane >> 4;
    const int nt2 = w & 3, oh = w >> 2;
    const int nloc = nt2 * 16 + col;
    short8v bf0 = *(const short8v*)(&xfrag[nloc][((0 + g) ^ (nloc & 7)) << 3]);
    short8v bf1 = *(const short8v*)(&xfrag[nloc][((4 + g) ^ (nloc & 7)) << 3]);
    const int n = n0 + nloc;
    const int nl = nloc;
    const size_t mblk = (size_t)b * 64 + (blockIdx.x & 63);
    short* kbase = kfrag + mblk * 1024;
    short* vbase = vfrag + mblk * 4096;
    const int mtk  = 2 * ((nl >> 2) & 1) + (nl >> 5);
    const int colk = 4 * ((nl >> 3) & 3) + (nl & 3);
    const int ks = nl >> 5, gv = (nl >> 3) & 3, jv = nl & 7;
    #pragma unroll
    for (int oi = 0; oi < 3; ++oi) {
        const int ot = oh * 3 + oi;
        short8v af0 = *(const short8v*)(&wfrag[ot][0][lane * 8]);   // lane = g*16+col
        short8v af1 = *(const short8v*)(&wfrag[ot][1][lane * 8]);
        f32x4 acc = 0.f;
        acc = __builtin_amdgcn_mfma_f32_16x16x32_bf16(af0, bf0, acc, 0, 0, 0);
        acc = __builtin_amdgcn_mfma_f32_16x16x32_bf16(af1, bf1, acc, 0, 0, 0);
        if (ot == 0) {          // q: rows o=4g+r, packed b64
            unsigned lo = pack_bf2(acc[0] + bias2[4*g+0], acc[1] + bias2[4*g+1]);
            unsigned hi = pack_bf2(acc[2] + bias2[4*g+2], acc[3] + bias2[4*g+3]);
            *(uint2*)(qT + ((size_t)b * N_ + n) * 16 + 4 * g) = make_uint2(lo, hi);
        } else if (ot == 1) {   // k: c = 4g+r, packed b64 into kfrag layout
            unsigned lo = pack_bf2(acc[0] + bias2[16+4*g+0], acc[1] + bias2[16+4*g+1]);
            unsigned hi = pack_bf2(acc[2] + bias2[16+4*g+2], acc[3] + bias2[16+4*g+3]);
            *(uint2*)(kbase + (((mtk * 2 + (g >> 1)) * 16 + colk) << 3) + 4 * (g & 1)) = make_uint2(lo, hi);
        } else {                // v: p = (ot-2)*16 + 4g + r, scalar b16 into vfrag layout
            #pragma unroll
            for (int r = 0; r < 4; ++r) {
                const int o = ot * 16 + 4 * g + r;
                vbase[(((ks * 4 + (ot - 2)) * 64 + gv * 16 + 4 * g + r) << 3) + jv] =
                    f2bf(acc[r] + bias2[o]);
            }
        }
    }
}

// ---------------- MFMA flash attention: zero-LDS, VGPR-slimmed for 5 waves/SIMD ----------------
// vs R16: (a) S accumulated as in-lane f32x4 (no ones-MFMA, no S accumulators in AGPR),
// cross-lane butterfly once after the loop; (b) V loaded in two 4-fragment halves
// (ks0 before QK, ks1 after QK issue); (c) launch_bounds min 5 waves/EU caps VGPR ~102.
__global__ __launch_bounds__(256, 5) void k_attn(const short* __restrict__ qT,
        const short* __restrict__ kfrag, const short* __restrict__ vfrag,
        short* __restrict__ apart) {
    const int wg  = blockIdx.x;
    const int swz = (wg & 7) * 128 + (wg >> 3);   // bijective (1024 = 8*128)
    const int b   = swz >> 8;
    const int mq  = (swz >> 5) & 7;
    const int nt  = swz & 31;
    const int n0  = nt << 7;

    const int t    = threadIdx.x;
    const int w    = t >> 6;
    const int lane = t & 63;
    const int g    = lane >> 4;   // 0..3
    const int col  = lane & 15;

    const short* qbase = qT + ((size_t)b * N_ + n0 + w * 32 + col) * 16;
    const short* kfb = kfrag + ((size_t)b * 64 + mq * 8) * 1024;
    const short* vfb = vfrag + ((size_t)b * 64 + mq * 8) * 4096;

    short8v a_q0 = 0, a_q1 = 0;
    if (g < 2) {
        a_q0 = *(const short8v*)(qbase + 8 * g);
        a_q1 = *(const short8v*)(qbase + 256 + 8 * g);   // +16 rows * 16 c
    }

    f32x4 acc0[4], acc1[4];
    #pragma unroll
    for (int pt = 0; pt < 4; ++pt) { acc0[pt] = 0.f; acc1[pt] = 0.f; }
    f32x4 Ssum0 = 0.f, Ssum1 = 0.f;

    for (int it = 0; it < 8; ++it) {
        const short* kit = kfb + it * 1024;
        const short* vit = vfb + it * 4096;
        // K fragments + V ks=0 half (issued before QK; consumed after softmax)
        short8v kr[4];
        #pragma unroll
        for (int mt = 0; mt < 4; ++mt) {
            kr[mt] = 0;
            if (g < 2) kr[mt] = *(const short8v*)(kit + ((mt * 2 + g) * 16 + col) * 8);
        }
        short8v vpreA[4];
        #pragma unroll
        for (int j = 0; j < 4; ++j)
            vpreA[j] = *(const short8v*)(vit + (j * 64 + g * 16 + col) * 8);
        // ---- QK, qs=0 ----
        f32x4 s[4];
        #pragma unroll
        for (int mt = 0; mt < 4; ++mt) {
            f32x4 z = 0.f;
            s[mt] = __builtin_amdgcn_mfma_f32_16x16x32_bf16(kr[mt], a_q0, z, 0, 0, 0);
        }
        // V ks=1 half: issue now, consumed after PV ks=0 (covered by softmax+PV)
        short8v vpreB[4];
        #pragma unroll
        for (int j = 0; j < 4; ++j)
            vpreB[j] = *(const short8v*)(vit + ((4 + j) * 64 + g * 16 + col) * 8);
        // softmax qs=0: exp2 (f32), in-lane S accumulate, pack to bf16 A-fragments
        union { unsigned u[4]; short8v v; } p0k0, p0k1, p1k0, p1k1;
        {
            f32x4 e0, e1, e2, e3;
            #pragma unroll
            for (int r = 0; r < 4; ++r) {
                e0[r] = exp2_fast(s[0][r]); e1[r] = exp2_fast(s[1][r]);
                e2[r] = exp2_fast(s[2][r]); e3[r] = exp2_fast(s[3][r]);
            }
            Ssum0 += (e0 + e1) + (e2 + e3);
            p0k0.u[0] = pack_bf2(e0[0], e0[1]); p0k0.u[1] = pack_bf2(e0[2], e0[3]);
            p0k0.u[2] = pack_bf2(e2[0], e2[1]); p0k0.u[3] = pack_bf2(e2[2], e2[3]);
            p0k1.u[0] = pack_bf2(e1[0], e1[1]); p0k1.u[1] = pack_bf2(e1[2], e1[3]);
            p0k1.u[2] = pack_bf2(e3[0], e3[1]); p0k1.u[3] = pack_bf2(e3[2], e3[3]);
        }
        // ---- QK, qs=1 ----
        #pragma unroll
        for (int mt = 0; mt < 4; ++mt) {
            f32x4 z = 0.f;
            s[mt] = __builtin_amdgcn_mfma_f32_16x16x32_bf16(kr[mt], a_q1, z, 0, 0, 0);
        }
        {
            f32x4 e0, e1, e2, e3;
            #pragma unroll
            for (int r = 0; r < 4; ++r) {
                e0[r] = exp2_fast(s[0][r]); e1[r] = exp2_fast(s[1][r]);
                e2[r] = exp2_fast(s[2][r]); e3[r] = exp2_fast(s[3][r]);
            }
            Ssum1 += (e0 + e1) + (e2 + e3);
            p1k0.u[0] = pack_bf2(e0[0], e0[1]); p1k0.u[1] = pack_bf2(e0[2], e0[3]);
            p1k0.u[2] = pack_bf2(e2[0], e2[1]); p1k0.u[3] = pack_bf2(e2[2], e2[3]);
            p1k1.u[0] = pack_bf2(e1[0], e1[1]); p1k1.u[1] = pack_bf2(e1[2], e1[3]);
            p1k1.u[2] = pack_bf2(e3[0], e3[1]); p1k1.u[3] = pack_bf2(e3[2], e3[3]);
        }
        // ---- PV: ks=0 uses vpreA, ks=1 uses vpreB ----
        #pragma unroll
        for (int pt = 0; pt < 4; ++pt) {
            acc0[pt] = __builtin_amdgcn_mfma_f32_16x16x32_bf16(p0k0.v, vpreA[pt], acc0[pt], 0, 0, 0);
            acc1[pt] = __builtin_amdgcn_mfma_f32_16x16x32_bf16(p1k0.v, vpreA[pt], acc1[pt], 0, 0, 0);
        }
        #pragma unroll
        for (int pt = 0; pt < 4; ++pt) {
            acc0[pt] = __builtin_amdgcn_mfma_f32_16x16x32_bf16(p0k1.v, vpreB[pt], acc0[pt], 0, 0, 0);
            acc1[pt] = __builtin_amdgcn_mfma_f32_16x16x32_bf16(p1k1.v, vpreB[pt], acc1[pt], 0, 0, 0);
        }
    }
    // ---- finalize S: horizontal + butterfly over g (masks 16, 32) ----
    float S0 = (Ssum0[0] + Ssum0[1]) + (Ssum0[2] + Ssum0[3]);
    float S1 = (Ssum1[0] + Ssum1[1]) + (Ssum1[2] + Ssum1[3]);
    S0 += __shfl_xor(S0, 16, 64);  S0 += __shfl_xor(S0, 32, 64);
    S1 += __shfl_xor(S1, 16, 64);  S1 += __shfl_xor(S1, 32, 64);
    // ---- emit partial: unnormalized bf16 O [128q][64p] + S[128] f32 ----
    short* po = apart + (size_t)((b * 8 + mq) * 32 + nt) * 8448;
    #pragma unroll
    for (int pt = 0; pt < 4; ++pt) {
        #pragma unroll
        for (int r = 0; r < 4; ++r) {
            po[(w * 32 + 4 * g + r) * 64 + pt * 16 + col]      = f2bf(acc0[pt][r]);
            po[(w * 32 + 16 + 4 * g + r) * 64 + pt * 16 + col] = f2bf(acc1[pt][r]);
        }
    }
    if (g == 0) {
        float* ms = (float*)(po + 8192);
        ms[w * 32 + col]      = S0;   // q = col (S[q] uniform across g after butterfly)
        ms[w * 32 + 16 + col] = S1;
    }
}

// ------- fused merge + silu + proj GEMM + BN: one block per (b, 32-n tile) -------
__global__ __launch_bounds__(256) void k_proj2(const short* __restrict__ apart,
        const float* __restrict__ x, const short* __restrict__ wbf,
        const float* __restrict__ beta, float* __restrict__ out) {
    __shared__ __align__(16) short ybf[32 * 256];   // 16 KB
    const int t  = threadIdx.x;
    const int nt = blockIdx.x;        // 0..127
    const int b  = blockIdx.y;
    const int n0 = nt << 5;

    {   // ---- stage A: merge 8 attn partials -> silu -> y[n][0..64) ----
        const int nn = t >> 3, pg = t & 7;
        const int qloc = ((nt & 3) << 5) + nn;
        const short* pbase = apart + (size_t)((b * 8) * 32 + (nt >> 2)) * 8448;
        float oacc[8] = {0.f, 0.f, 0.f, 0.f, 0.f, 0.f, 0.f, 0.f};
        float Ssum = 0.f;
        #pragma unroll
        for (int k = 0; k < 8; ++k) {
            const short* pk = pbase + (size_t)k * 32 * 8448;
            Ssum += ((const float*)(pk + 8192))[qloc];
            short8v a = *(const short8v*)(pk + qloc * 64 + pg * 8);
            #pragma unroll
            for (int j = 0; j < 8; ++j) oacc[j] += bf2f(a[j]);
        }
        const float inv = 1.0f / Ssum;
        const int slot = pg ^ (nn & 7);
        *(uint4*)(ybf + nn * 256 + slot * 8) = make_uint4(
            pack_bf2(silu_(oacc[0] * inv), silu_(oacc[1] * inv)),
            pack_bf2(silu_(oacc[2] * inv), silu_(oacc[3] * inv)),
            pack_bf2(silu_(oacc[4] * inv), silu_(oacc[5] * inv)),
            pack_bf2(silu_(oacc[6] * inv), silu_(oacc[7] * inv)));
    }
    {   // ---- stage B: x2 -> silu -> y[n][64..256) ----
        const int nn = t & 31, cg = t >> 5;            // 8 c-groups x 24 c
        #pragma unroll
        for (int s3 = 0; s3 < 3; ++s3) {
            const int cb = 64 + cg * 24 + s3 * 8;
            unsigned pk4[4];
            #pragma unroll
            for (int j = 0; j < 4; ++j) {
                float v0 = x[((size_t)(b * C_ + cb + 2 * j)) * N_ + n0 + nn];
                float v1 = x[((size_t)(b * C_ + cb + 2 * j + 1)) * N_ + n0 + nn];
                pk4[j] = pack_bf2(silu_(v0), silu_(v1));
            }
            const int slot = (8 + cg * 3 + s3) ^ (nn & 7);
            *(uint4*)(ybf + nn * 256 + slot * 8) = make_uint4(pk4[0], pk4[1], pk4[2], pk4[3]);
        }
    }
    __syncthreads();
    // ---- GEMM: wave w -> o in [w*64, w*64+64), n in [n0, n0+32) ----
    const int w = t >> 6, lane = t & 63;
    const int col = lane & 15, g = lane >> 4;
    const int o_base = w << 6;
    f32x4 acc[4][2];
    #pragma unroll
    for (int ot = 0; ot < 4; ++ot) { acc[ot][0] = 0.f; acc[ot][1] = 0.f; }
    #pragma unroll
    for (int kk = 0; kk < 8; ++kk) {
        short8v bf0 = *(const short8v*)(ybf + col * 256 + (((kk * 4 + g) ^ (col & 7)) << 3));
        short8v bf1 = *(const short8v*)(ybf + (16 + col) * 256 + (((kk * 4 + g) ^ (col & 7)) << 3));
        #pragma unroll
        for (int ot = 0; ot < 4; ++ot) {
            short8v af = *(const short8v*)(wbf + (size_t)(o_base + ot * 16 + col) * C_ + kk * 32 + g * 8);
            acc[ot][0] = __builtin_amdgcn_mfma_f32_16x16x32_bf16(af, bf0, acc[ot][0], 0, 0, 0);
            acc[ot][1] = __builtin_amdgcn_mfma_f32_16x16x32_bf16(af, bf1, acc[ot][1], 0, 0, 0);
        }
    }
    #pragma unroll
    for (int ot = 0; ot < 4; ++ot) {
        #pragma unroll
        for (int r = 0; r < 4; ++r) {
            const int o = o_base + ot * 16 + 4 * g + r;
            const float be = beta[o];
            float* po = out + ((size_t)(b * C_ + o)) * N_ + n0 + col;
            po[0]  = acc[ot][0][r] + be;
            po[16] = acc[ot][1][r] + be;
        }
    }
}

extern "C" void kernel_launch(void* const* d_in, const int* in_sizes, int n_in,
                              void* d_out, int out_size, void* d_ws, size_t ws_size,
                              hipStream_t stream) {
    const float* x   = (const float*)d_in[0];
    const float* gnw = (const float*)d_in[1];
    const float* gnb = (const float*)d_in[2];
    const float* qw  = (const float*)d_in[3];
    const float* qbw = (const float*)d_in[4];
    const float* qbb = (const float*)d_in[5];
    const float* qrm = (const float*)d_in[6];
    const float* qrv = (const float*)d_in[7];
    const float* pw  = (const float*)d_in[8];
    const float* pbw = (const float*)d_in[9];
    const float* pbb = (const float*)d_in[10];
    const float* prm = (const float*)d_in[11];
    const float* prv = (const float*)d_in[12];
    float* out = (float*)d_out;
    char* wsb = (char*)d_ws;

    float* part  = (float*)wsb;                       // 2 KB
    short* wbf   = (short*)(wsb + 4096);              // 128 KB
    float* beta  = (float*)(wsb + 135168);            // 1 KB (pad to 4 KB)
    short* qTb   = (short*)(wsb + 139264);            // 512 KB
    short* kfrag = (short*)(wsb + 663552);            // 512 KB
    short* vfrag = (short*)(wsb + 1187840);           // 2 MB
    short* apart = (short*)(wsb + 3284992);           // 1024*16896B = 17.3 MB

    k_gnw<<<512, 256, 0, stream>>>(x, part, pw, pbw, pbb, prm, prv, wbf, beta);
    k_qkv<<<256, 512, 0, stream>>>(x, gnw, gnb, qw, qbw, qbb, qrm, qrv, part, qTb, kfrag, vfrag);
    k_attn<<<1024, 256, 0, stream>>>(qTb, kfrag, vfrag, apart);
    k_proj2<<<dim3(128, 4), 256, 0, stream>>>(apart, x, wbf, beta, out);
}

// Round 18
// 55.432 us; speedup vs baseline: 1.1650x; 1.1650x over previous
//
#include <hip/hip_runtime.h>
#include <hip/hip_bf16.h>
#include <math.h>

static constexpr int B_ = 4;
static constexpr int C_ = 256;
static constexpr int PD_ = 64;
static constexpr int N_ = 4096;
static constexpr int O96_ = 96;
static constexpr float EPS_ = 1e-5f;
static constexpr float SCALE_ = 0.25f;   // 16^-0.5
static constexpr float LOG2E_ = 1.4426950408889634f;

typedef __attribute__((ext_vector_type(8))) short short8v;
typedef __attribute__((ext_vector_type(4))) float f32x4;

__device__ inline short f2bf(float x) {
    __hip_bfloat16 h = __float2bfloat16(x);   // hw RNE cvt
    short r; __builtin_memcpy(&r, &h, 2); return r;
}
__device__ inline float bf2f(short s) {
    union { float f; unsigned u; } v; v.u = ((unsigned)(unsigned short)s) << 16;
    return v.f;
}
__device__ inline unsigned pack_bf2(float lo, float hi) {
    return ((unsigned)(unsigned short)f2bf(hi) << 16) | (unsigned)(unsigned short)f2bf(lo);
}
__device__ inline float silu_(float v) { return v / (1.0f + __expf(-v)); }
__device__ inline float exp2_fast(float x) {
#if __has_builtin(__builtin_amdgcn_exp2f)
    return __builtin_amdgcn_exp2f(x);
#else
    return __expf(x * 0.6931471805599453f);
#endif
}

// ------- fused: blocks 0-255 GroupNorm partial sums (float4); 256-511 proj-weight cvt -------
__global__ __launch_bounds__(256) void k_gnw(const float* __restrict__ x,
        float* __restrict__ part,
        const float* __restrict__ pw,  const float* __restrict__ bnw,
        const float* __restrict__ bnb, const float* __restrict__ rm,
        const float* __restrict__ rv,  short* __restrict__ wbf,
        float* __restrict__ beta) {
    if (blockIdx.x >= 256) {               // ---- wcvt ----
        const int idx = (blockIdx.x - 256) * 256 + threadIdx.x;   // 0..65535
        const int o = idx >> 8, c = idx & 255;
        const float inv = bnw[o] * rsqrtf(rv[o] + EPS_);
        wbf[idx] = f2bf(pw[idx] * inv);
        if (c == 0) beta[o] = bnb[o] - rm[o] * inv;
        return;
    }
    const int blk = blockIdx.x;            // b*64 + c
    const int b = blk >> 6, c = blk & 63;
    const float4* p4 = (const float4*)(x + (size_t)(b * C_ + c) * N_);
    float s = 0.f, q = 0.f;
    #pragma unroll
    for (int i = 0; i < 4; ++i) {
        float4 v = p4[threadIdx.x + i * 256];
        s += v.x + v.y + v.z + v.w;
        q += v.x * v.x + v.y * v.y + v.z * v.z + v.w * v.w;
    }
    for (int d = 1; d < 64; d <<= 1) {
        s += __shfl_xor(s, d, 64);
        q += __shfl_xor(q, d, 64);
    }
    __shared__ float ls[4], lq[4];
    const int lane = threadIdx.x & 63, wid = threadIdx.x >> 6;
    if (lane == 0) { ls[wid] = s; lq[wid] = q; }
    __syncthreads();
    if (threadIdx.x == 0) {
        part[2 * blk]     = ls[0] + ls[1] + ls[2] + ls[3];
        part[2 * blk + 1] = lq[0] + lq[1] + lq[2] + lq[3];
    }
}

// ------- qkv as bf16 MFMA GEMM: GN+BN fully folded into w''/bias2 (R16 form) ------
__global__ __launch_bounds__(512) void k_qkv(const float* __restrict__ x,
        const float* __restrict__ gnw, const float* __restrict__ gnb,
        const float* __restrict__ qw,  const float* __restrict__ bnw,
        const float* __restrict__ bnb, const float* __restrict__ rm,
        const float* __restrict__ rv,  const float* __restrict__ part,
        short* __restrict__ qT, short* __restrict__ kfrag, short* __restrict__ vfrag) {
    __shared__ __align__(16) short wfrag[6][2][512];  // 12 KB  [ot][kk][(g*16+col)*8+j]
    __shared__ __align__(16) short xfrag[64][64];     // 8 KB   [n][(c8^(n&7))*8 + (c&7)]
    __shared__ float bias2[96];
    __shared__ float musr[2];
    const int t = threadIdx.x;
    const int b = blockIdx.x >> 6;
    const int n0 = (blockIdx.x & 63) << 6;
    if (t < 64) {                          // folded gn_fin
        float s = part[2 * (b * 64 + t)];
        float q = part[2 * (b * 64 + t) + 1];
        for (int d = 1; d < 64; d <<= 1) {
            s += __shfl_xor(s, d, 64);
            q += __shfl_xor(q, d, 64);
        }
        if (t == 0) {
            const float inv_n = 1.0f / (float)(PD_ * N_);
            float mu = s * inv_n;
            float var = q * inv_n - mu * mu;
            musr[0] = mu;
            musr[1] = rsqrtf(var + EPS_);
        }
    }
    {   // stage raw x1 tile -> bf16 xfrag (GN folded into weights, not here)
        const int nq = t & 15, c0 = t >> 4;            // c0 0..31
        #pragma unroll
        for (int pass = 0; pass < 2; ++pass) {
            const int c = c0 + pass * 32;
            float4 v4 = *(const float4*)(x + ((size_t)(b * C_ + c)) * N_ + n0 + nq * 4);
            const int c8 = c >> 3, cj = c & 7;
            float vv[4] = {v4.x, v4.y, v4.z, v4.w};
            #pragma unroll
            for (int e = 0; e < 4; ++e) {
                const int n = nq * 4 + e;
                xfrag[n][((c8 ^ (n & 7)) << 3) + cj] = f2bf(vv[e]);
            }
        }
    }
    __syncthreads();
    const float mu = musr[0], rs = musr[1];
    if (t < 96) {                          // build w'' fragments + bias2
        const int o = t;
        float inv  = bnw[o] * rsqrtf(rv[o] + EPS_);
        float bet  = bnb[o] - rm[o] * inv;
        if (o < 16) { inv *= SCALE_ * LOG2E_; bet *= SCALE_ * LOG2E_; }
        const float* wr = qw + o * PD_;
        const int ot = o >> 4, colo = o & 15;
        float bacc = 0.f;
        #pragma unroll
        for (int c = 0; c < PD_; ++c) {
            const float ga = rs * gnw[c];
            const float gb = gnb[c] - mu * ga;
            const float wv = wr[c];
            bacc += wv * gb;
            wfrag[ot][c >> 5][((((c >> 3) & 3) * 16 + colo) << 3) + (c & 7)] = f2bf(wv * ga * inv);
        }
        bias2[o] = bet + inv * bacc;
    }
    __syncthreads();
    // MFMA: wave w: n-tile nt2 = w&3, o-half oh = w>>2 (ot = 3*oh .. 3*oh+2)
    const int w = t >> 6, lane = t & 63;
    const int col = lane & 15, g = lane >> 4;
    const int nt2 = w & 3, oh = w >> 2;
    const int nloc = nt2 * 16 + col;
    short8v bf0 = *(const short8v*)(&xfrag[nloc][((0 + g) ^ (nloc & 7)) << 3]);
    short8v bf1 = *(const short8v*)(&xfrag[nloc][((4 + g) ^ (nloc & 7)) << 3]);
    const int n = n0 + nloc;
    const int nl = nloc;
    const size_t mblk = (size_t)b * 64 + (blockIdx.x & 63);
    short* kbase = kfrag + mblk * 1024;
    short* vbase = vfrag + mblk * 4096;
    const int mtk  = 2 * ((nl >> 2) & 1) + (nl >> 5);
    const int colk = 4 * ((nl >> 3) & 3) + (nl & 3);
    const int ks = nl >> 5, gv = (nl >> 3) & 3, jv = nl & 7;
    #pragma unroll
    for (int oi = 0; oi < 3; ++oi) {
        const int ot = oh * 3 + oi;
        short8v af0 = *(const short8v*)(&wfrag[ot][0][lane * 8]);   // lane = g*16+col
        short8v af1 = *(const short8v*)(&wfrag[ot][1][lane * 8]);
        f32x4 acc = 0.f;
        acc = __builtin_amdgcn_mfma_f32_16x16x32_bf16(af0, bf0, acc, 0, 0, 0);
        acc = __builtin_amdgcn_mfma_f32_16x16x32_bf16(af1, bf1, acc, 0, 0, 0);
        if (ot == 0) {          // q: rows o=4g+r, packed b64
            unsigned lo = pack_bf2(acc[0] + bias2[4*g+0], acc[1] + bias2[4*g+1]);
            unsigned hi = pack_bf2(acc[2] + bias2[4*g+2], acc[3] + bias2[4*g+3]);
            *(uint2*)(qT + ((size_t)b * N_ + n) * 16 + 4 * g) = make_uint2(lo, hi);
        } else if (ot == 1) {   // k: c = 4g+r, packed b64 into kfrag layout
            unsigned lo = pack_bf2(acc[0] + bias2[16+4*g+0], acc[1] + bias2[16+4*g+1]);
            unsigned hi = pack_bf2(acc[2] + bias2[16+4*g+2], acc[3] + bias2[16+4*g+3]);
            *(uint2*)(kbase + (((mtk * 2 + (g >> 1)) * 16 + colk) << 3) + 4 * (g & 1)) = make_uint2(lo, hi);
        } else {                // v: p = (ot-2)*16 + 4g + r, scalar b16 into vfrag layout
            #pragma unroll
            for (int r = 0; r < 4; ++r) {
                const int o = ot * 16 + 4 * g + r;
                vbase[(((ks * 4 + (ot - 2)) * 64 + gv * 16 + 4 * g + r) << 3) + jv] =
                    f2bf(acc[r] + bias2[o]);
            }
        }
    }
}

// ---------------- MFMA flash attention: zero-LDS, fully barrier-free (R16/R14 best form) ----------------
__global__ __launch_bounds__(256) void k_attn(const short* __restrict__ qT,
        const short* __restrict__ kfrag, const short* __restrict__ vfrag,
        short* __restrict__ apart) {
    const int wg  = blockIdx.x;
    const int swz = (wg & 7) * 128 + (wg >> 3);   // bijective (1024 = 8*128)
    const int b   = swz >> 8;
    const int mq  = (swz >> 5) & 7;
    const int nt  = swz & 31;
    const int n0  = nt << 7;

    const int t    = threadIdx.x;
    const int w    = t >> 6;
    const int lane = t & 63;
    const int g    = lane >> 4;   // 0..3
    const int col  = lane & 15;

    const short* qbase = qT + ((size_t)b * N_ + n0 + w * 32 + col) * 16;
    const short* kfb = kfrag + ((size_t)b * 64 + mq * 8) * 1024;
    const short* vfb = vfrag + ((size_t)b * 64 + mq * 8) * 4096;

    short8v a_q0 = 0, a_q1 = 0;
    if (g < 2) {
        a_q0 = *(const short8v*)(qbase + 8 * g);
        a_q1 = *(const short8v*)(qbase + 256 + 8 * g);   // +16 rows * 16 c
    }
    short8v onesf = 0;
    if (col == 0) {
        #pragma unroll
        for (int j = 0; j < 8; ++j) onesf[j] = (short)0x3F80;   // bf16 1.0
    }

    f32x4 acc0[5], acc1[5];
    #pragma unroll
    for (int pt = 0; pt < 5; ++pt) { acc0[pt] = 0.f; acc1[pt] = 0.f; }

    for (int it = 0; it < 8; ++it) {
        const short* kit = kfb + it * 1024;
        const short* vit = vfb + it * 4096;
        // K fragments (shared by both q subtiles)
        short8v kr[4];
        #pragma unroll
        for (int mt = 0; mt < 4; ++mt) {
            kr[mt] = 0;
            if (g < 2) kr[mt] = *(const short8v*)(kit + ((mt * 2 + g) * 16 + col) * 8);
        }
        // V fragments (shared): 1KB-contiguous coalesced loads, issued early
        short8v vpre[8];
        #pragma unroll
        for (int j = 0; j < 8; ++j)
            vpre[j] = *(const short8v*)(vit + (j * 64 + g * 16 + col) * 8);
        // ---- QK + in-register softmax, qs=0 ----
        f32x4 s[4];
        #pragma unroll
        for (int mt = 0; mt < 4; ++mt) {
            f32x4 z = 0.f;
            s[mt] = __builtin_amdgcn_mfma_f32_16x16x32_bf16(kr[mt], a_q0, z, 0, 0, 0);
        }
        union { unsigned u[4]; short8v v; } p0k0, p0k1, p1k0, p1k1;
        p0k0.u[0] = pack_bf2(exp2_fast(s[0][0]), exp2_fast(s[0][1]));
        p0k0.u[1] = pack_bf2(exp2_fast(s[0][2]), exp2_fast(s[0][3]));
        p0k0.u[2] = pack_bf2(exp2_fast(s[2][0]), exp2_fast(s[2][1]));
        p0k0.u[3] = pack_bf2(exp2_fast(s[2][2]), exp2_fast(s[2][3]));
        p0k1.u[0] = pack_bf2(exp2_fast(s[1][0]), exp2_fast(s[1][1]));
        p0k1.u[1] = pack_bf2(exp2_fast(s[1][2]), exp2_fast(s[1][3]));
        p0k1.u[2] = pack_bf2(exp2_fast(s[3][0]), exp2_fast(s[3][1]));
        p0k1.u[3] = pack_bf2(exp2_fast(s[3][2]), exp2_fast(s[3][3]));
        // ---- QK + softmax, qs=1 ----
        #pragma unroll
        for (int mt = 0; mt < 4; ++mt) {
            f32x4 z = 0.f;
            s[mt] = __builtin_amdgcn_mfma_f32_16x16x32_bf16(kr[mt], a_q1, z, 0, 0, 0);
        }
        p1k0.u[0] = pack_bf2(exp2_fast(s[0][0]), exp2_fast(s[0][1]));
        p1k0.u[1] = pack_bf2(exp2_fast(s[0][2]), exp2_fast(s[0][3]));
        p1k0.u[2] = pack_bf2(exp2_fast(s[2][0]), exp2_fast(s[2][1]));
        p1k0.u[3] = pack_bf2(exp2_fast(s[2][2]), exp2_fast(s[2][3]));
        p1k1.u[0] = pack_bf2(exp2_fast(s[1][0]), exp2_fast(s[1][1]));
        p1k1.u[1] = pack_bf2(exp2_fast(s[1][2]), exp2_fast(s[1][3]));
        p1k1.u[2] = pack_bf2(exp2_fast(s[3][0]), exp2_fast(s[3][1]));
        p1k1.u[3] = pack_bf2(exp2_fast(s[3][2]), exp2_fast(s[3][3]));
        // ---- PV (P already in A-fragment order); ones-col accumulates S ----
        acc0[4] = __builtin_amdgcn_mfma_f32_16x16x32_bf16(p0k0.v, onesf, acc0[4], 0, 0, 0);
        acc0[4] = __builtin_amdgcn_mfma_f32_16x16x32_bf16(p0k1.v, onesf, acc0[4], 0, 0, 0);
        acc1[4] = __builtin_amdgcn_mfma_f32_16x16x32_bf16(p1k0.v, onesf, acc1[4], 0, 0, 0);
        acc1[4] = __builtin_amdgcn_mfma_f32_16x16x32_bf16(p1k1.v, onesf, acc1[4], 0, 0, 0);
        #pragma unroll
        for (int pt = 0; pt < 4; ++pt) {
            acc0[pt] = __builtin_amdgcn_mfma_f32_16x16x32_bf16(p0k0.v, vpre[pt],     acc0[pt], 0, 0, 0);
            acc0[pt] = __builtin_amdgcn_mfma_f32_16x16x32_bf16(p0k1.v, vpre[4 + pt], acc0[pt], 0, 0, 0);
            acc1[pt] = __builtin_amdgcn_mfma_f32_16x16x32_bf16(p1k0.v, vpre[pt],     acc1[pt], 0, 0, 0);
            acc1[pt] = __builtin_amdgcn_mfma_f32_16x16x32_bf16(p1k1.v, vpre[4 + pt], acc1[pt], 0, 0, 0);
        }
    }
    // ---- emit partial: unnormalized bf16 O [128q][64p] + S[128] f32 ----
    short* po = apart + (size_t)((b * 8 + mq) * 32 + nt) * 8448;
    #pragma unroll
    for (int pt = 0; pt < 4; ++pt) {
        #pragma unroll
        for (int r = 0; r < 4; ++r) {
            po[(w * 32 + 4 * g + r) * 64 + pt * 16 + col]      = f2bf(acc0[pt][r]);
            po[(w * 32 + 16 + 4 * g + r) * 64 + pt * 16 + col] = f2bf(acc1[pt][r]);
        }
    }
    if (col == 0) {
        float* ms = (float*)(po + 8192);
        #pragma unroll
        for (int r = 0; r < 4; ++r) {
            ms[w * 32 + 4 * g + r]      = acc0[4][r];
            ms[w * 32 + 16 + 4 * g + r] = acc1[4][r];
        }
    }
}

// ------- fused merge + silu + proj GEMM + BN: one block per (b, 32-n tile) -------
__global__ __launch_bounds__(256) void k_proj2(const short* __restrict__ apart,
        const float* __restrict__ x, const short* __restrict__ wbf,
        const float* __restrict__ beta, float* __restrict__ out) {
    __shared__ __align__(16) short ybf[32 * 256];   // 16 KB
    const int t  = threadIdx.x;
    const int nt = blockIdx.x;        // 0..127
    const int b  = blockIdx.y;
    const int n0 = nt << 5;

    {   // ---- stage A: merge 8 attn partials -> silu -> y[n][0..64) ----
        const int nn = t >> 3, pg = t & 7;
        const int qloc = ((nt & 3) << 5) + nn;
        const short* pbase = apart + (size_t)((b * 8) * 32 + (nt >> 2)) * 8448;
        float oacc[8] = {0.f, 0.f, 0.f, 0.f, 0.f, 0.f, 0.f, 0.f};
        float Ssum = 0.f;
        #pragma unroll
        for (int k = 0; k < 8; ++k) {
            const short* pk = pbase + (size_t)k * 32 * 8448;
            Ssum += ((const float*)(pk + 8192))[qloc];
            short8v a = *(const short8v*)(pk + qloc * 64 + pg * 8);
            #pragma unroll
            for (int j = 0; j < 8; ++j) oacc[j] += bf2f(a[j]);
        }
        const float inv = 1.0f / Ssum;
        const int slot = pg ^ (nn & 7);
        *(uint4*)(ybf + nn * 256 + slot * 8) = make_uint4(
            pack_bf2(silu_(oacc[0] * inv), silu_(oacc[1] * inv)),
            pack_bf2(silu_(oacc[2] * inv), silu_(oacc[3] * inv)),
            pack_bf2(silu_(oacc[4] * inv), silu_(oacc[5] * inv)),
            pack_bf2(silu_(oacc[6] * inv), silu_(oacc[7] * inv)));
    }
    {   // ---- stage B: x2 -> silu -> y[n][64..256) ----
        const int nn = t & 31, cg = t >> 5;            // 8 c-groups x 24 c
        #pragma unroll
        for (int s3 = 0; s3 < 3; ++s3) {
            const int cb = 64 + cg * 24 + s3 * 8;
            unsigned pk4[4];
            #pragma unroll
            for (int j = 0; j < 4; ++j) {
                float v0 = x[((size_t)(b * C_ + cb + 2 * j)) * N_ + n0 + nn];
                float v1 = x[((size_t)(b * C_ + cb + 2 * j + 1)) * N_ + n0 + nn];
                pk4[j] = pack_bf2(silu_(v0), silu_(v1));
            }
            const int slot = (8 + cg * 3 + s3) ^ (nn & 7);
            *(uint4*)(ybf + nn * 256 + slot * 8) = make_uint4(pk4[0], pk4[1], pk4[2], pk4[3]);
        }
    }
    __syncthreads();
    // ---- GEMM: wave w -> o in [w*64, w*64+64), n in [n0, n0+32) ----
    const int w = t >> 6, lane = t & 63;
    const int col = lane & 15, g = lane >> 4;
    const int o_base = w << 6;
    f32x4 acc[4][2];
    #pragma unroll
    for (int ot = 0; ot < 4; ++ot) { acc[ot][0] = 0.f; acc[ot][1] = 0.f; }
    #pragma unroll
    for (int kk = 0; kk < 8; ++kk) {
        short8v bf0 = *(const short8v*)(ybf + col * 256 + (((kk * 4 + g) ^ (col & 7)) << 3));
        short8v bf1 = *(const short8v*)(ybf + (16 + col) * 256 + (((kk * 4 + g) ^ (col & 7)) << 3));
        #pragma unroll
        for (int ot = 0; ot < 4; ++ot) {
            short8v af = *(const short8v*)(wbf + (size_t)(o_base + ot * 16 + col) * C_ + kk * 32 + g * 8);
            acc[ot][0] = __builtin_amdgcn_mfma_f32_16x16x32_bf16(af, bf0, acc[ot][0], 0, 0, 0);
            acc[ot][1] = __builtin_amdgcn_mfma_f32_16x16x32_bf16(af, bf1, acc[ot][1], 0, 0, 0);
        }
    }
    #pragma unroll
    for (int ot = 0; ot < 4; ++ot) {
        #pragma unroll
        for (int r = 0; r < 4; ++r) {
            const int o = o_base + ot * 16 + 4 * g + r;
            const float be = beta[o];
            float* po = out + ((size_t)(b * C_ + o)) * N_ + n0 + col;
            po[0]  = acc[ot][0][r] + be;
            po[16] = acc[ot][1][r] + be;
        }
    }
}

extern "C" void kernel_launch(void* const* d_in, const int* in_sizes, int n_in,
                              void* d_out, int out_size, void* d_ws, size_t ws_size,
                              hipStream_t stream) {
    const float* x   = (const float*)d_in[0];
    const float* gnw = (const float*)d_in[1];
    const float* gnb = (const float*)d_in[2];
    const float* qw  = (const float*)d_in[3];
    const float* qbw = (const float*)d_in[4];
    const float* qbb = (const float*)d_in[5];
    const float* qrm = (const float*)d_in[6];
    const float* qrv = (const float*)d_in[7];
    const float* pw  = (const float*)d_in[8];
    const float* pbw = (const float*)d_in[9];
    const float* pbb = (const float*)d_in[10];
    const float* prm = (const float*)d_in[11];
    const float* prv = (const float*)d_in[12];
    float* out = (float*)d_out;
    char* wsb = (char*)d_ws;

    float* part  = (float*)wsb;                       // 2 KB
    short* wbf   = (short*)(wsb + 4096);              // 128 KB
    float* beta  = (float*)(wsb + 135168);            // 1 KB (pad to 4 KB)
    short* qTb   = (short*)(wsb + 139264);            // 512 KB
    short* kfrag = (short*)(wsb + 663552);            // 512 KB
    short* vfrag = (short*)(wsb + 1187840);           // 2 MB
    short* apart = (short*)(wsb + 3284992);           // 1024*16896B = 17.3 MB

    k_gnw<<<512, 256, 0, stream>>>(x, part, pw, pbw, pbb, prm, prv, wbf, beta);
    k_qkv<<<256, 512, 0, stream>>>(x, gnw, gnb, qw, qbw, qbb, qrm, qrv, part, qTb, kfrag, vfrag);
    k_attn<<<1024, 256, 0, stream>>>(qTb, kfrag, vfrag, apart);
    k_proj2<<<dim3(128, 4), 256, 0, stream>>>(apart, x, wbf, beta, out);
}